// Round 10
// baseline (156.281 us; speedup 1.0000x reference)
//
#include <hip/hip_runtime.h>
#include <stdint.h>

#define NROWS 2048
#define DDIM  9216
#define TILE  160
#define NT160 13                      // ceil(2048/160) worst case
#define NTRI160 91                    // 13*14/2 worst-case triangle tiles
#define KS    8                       // K-slices (one per XCD)
#define KSLEN 1152                    // DDIM/KS
#define BK    64                      // K-step per stage
#define KIT   18                      // KSLEN/BK

typedef unsigned short u16;
typedef __bf16 bf16x8 __attribute__((ext_vector_type(8)));
typedef float  f32x4  __attribute__((ext_vector_type(4)));

// ws layout: meta[0..4096): [0] int A, [1] float sq, [2] int dcnt, [8..15] ctr[8]
//            [4096..) u16 nf[2048][9216]                    (37.75 MB)
//            [P_OFF..) float P[91][8][4][6400] partials     (74.5 MB max)
#define NF_OFF 4096ull
#define P_OFF  (NF_OFF + 2048ull * 9216ull * 2ull)

__device__ __forceinline__ u16 f2bf(float f) {
    uint32_t x = __float_as_uint(f);
    x += 0x7fffu + ((x >> 16) & 1u);          // round-to-nearest-even
    return (u16)(x >> 16);
}

__device__ __forceinline__ void gload16(const u16* g, u16* l) {
    __builtin_amdgcn_global_load_lds(
        (const __attribute__((address_space(1))) uint32_t*)g,
        (__attribute__((address_space(3))) uint32_t*)l, 16, 0, 0);
}

// ---------------- kernel 1: census + per-row stats + normalize + compact --------
__global__ __launch_bounds__(256) void stats_kernel(const float* __restrict__ wgt,
                                                    const float* __restrict__ mask,
                                                    u16* __restrict__ nf,
                                                    int* __restrict__ meta) {
    int n = blockIdx.x, tid = threadIdx.x;
    int w = tid >> 6, l = tid & 63;
    int c_pre = 0, c_tot = 0;                 // census: actives before n / total
#pragma unroll
    for (int r = 0; r < 8; ++r) {
        int j = tid * 8 + r;
        int a = (mask[j] != 0.0f) ? 1 : 0;
        c_tot += a;
        if (j < n) c_pre += a;
    }
#pragma unroll
    for (int o = 32; o > 0; o >>= 1) {
        c_pre += __shfl_down(c_pre, o);
        c_tot += __shfl_down(c_tot, o);
    }
    __shared__ int sp[4], st[4];
    __shared__ float rs[4], rss[4], smean, sinv;
    if (l == 0) { sp[w] = c_pre; st[w] = c_tot; }
    __syncthreads();
    int slot = sp[0] + sp[1] + sp[2] + sp[3];
    if (n == 0 && tid == 0) {
        meta[0] = st[0] + st[1] + st[2] + st[3];  // A
        meta[1] = 0;                              // sq (float 0.0 bits)
        meta[2] = 0;                              // dcnt
#pragma unroll
        for (int q = 0; q < 8; ++q) meta[8 + q] = 0;   // kslice work-queue ctrs
    }
    if (mask[n] == 0.0f) return;              // block-uniform: syncs below safe
    const float4* row = (const float4*)(wgt + (size_t)n * DDIM);
    float4 v[9];
    float s = 0.f, ss = 0.f;
#pragma unroll
    for (int i = 0; i < 9; ++i) {
        v[i] = row[tid + 256 * i];
        s  += v[i].x + v[i].y + v[i].z + v[i].w;
        ss += v[i].x * v[i].x + v[i].y * v[i].y + v[i].z * v[i].z + v[i].w * v[i].w;
    }
#pragma unroll
    for (int o = 32; o > 0; o >>= 1) { s += __shfl_down(s, o); ss += __shfl_down(ss, o); }
    if (l == 0) { rs[w] = s; rss[w] = ss; }
    __syncthreads();
    if (tid == 0) {
        float S  = rs[0] + rs[1] + rs[2] + rs[3];
        float SS = rss[0] + rss[1] + rss[2] + rss[3];
        float mean = S / (float)DDIM;
        float var  = SS / (float)DDIM - mean * mean;
        float sd   = sqrtf(fmaxf(var, 0.f));
        if (sd == 0.f) sd = 1.f;              // reference: std==0 -> 1
        smean = mean; sinv = 1.f / sd;
    }
    __syncthreads();
    float mean = smean, inv = sinv;
    u16* dst = nf + (size_t)slot * DDIM;
#pragma unroll
    for (int i = 0; i < 9; ++i) {
        int e = (tid + 256 * i) * 4;
        uint32_t lo = (uint32_t)f2bf((v[i].x - mean) * inv) |
                      ((uint32_t)f2bf((v[i].y - mean) * inv) << 16);
        uint32_t hi = (uint32_t)f2bf((v[i].z - mean) * inv) |
                      ((uint32_t)f2bf((v[i].w - mean) * inv) << 16);
        uint2 u; u.x = lo; u.y = hi;
        *(uint2*)(dst + e) = u;
    }
}

// ---------------- kernel 2: 160x160-tile partial GEMM, XCD-self-claimed K-split --
// R6 compute core verbatim. NEW: blocks read their OWN XCD via
// s_getreg(HW_REG_XCC_ID) [HW-verified, m09] and claim tile slots from
// per-kslice atomic work queues, preferring k == own XCD -> staging is
// guaranteed own-L2 (2.36 MB slab) instead of hoping bid%8 lands right.
// Correctness is dispatch-independent: atomicAdd hands out each (k,slot<ntri)
// exactly once; blocks that exhaust a queue sweep all 8 (k = xcc^pass), so
// every slot is claimed no matter how the CP places blocks (G16-safe).
// vmcnt(0) drain after P-stores keeps the counted-vmcnt pipeline sound when
// a block claims a second tile.
template<bool DIAG>
__device__ __forceinline__ void stage(const u16* pA, const u16* pB, int kt,
                                      u16* buf, int w) {
    const u16* a = pA + kt * BK;
    u16* Ad = buf + w * 2560;                 // 40 rows x 64 u16 per wave
#pragma unroll
    for (int i = 0; i < 5; ++i)
        gload16(a + (size_t)(8 * i) * DDIM, Ad + i * 512);
    if (!DIAG) {
        const u16* b = pB + kt * BK;
        u16* Bd = buf + 10240 + w * 2560;     // B half of the stage buffer
#pragma unroll
        for (int i = 0; i < 5; ++i)
            gload16(b + (size_t)(8 * i) * DDIM, Bd + i * 512);
    }
}

template<bool DIAG>
__device__ __forceinline__ void compute(const u16* buf, int wr, int wc,
                                        int m16, int quad, f32x4 acc[5][5]) {
    const u16* Ab = buf;
    const u16* Bb = DIAG ? buf : buf + 10240;
#pragma unroll
    for (int kk = 0; kk < 2; ++kk) {
        int sw = ((((kk << 2) | quad) ^ (m16 & 7)) << 3);
        bf16x8 af[5], bfr[5];
#pragma unroll
        for (int fm = 0; fm < 5; ++fm)
            af[fm] = *(const bf16x8*)&Ab[(wr * 80 + fm * 16 + m16) * 64 + sw];
#pragma unroll
        for (int fn = 0; fn < 5; ++fn)
            bfr[fn] = *(const bf16x8*)&Bb[(wc * 80 + fn * 16 + m16) * 64 + sw];
#pragma unroll
        for (int fm = 0; fm < 5; ++fm)
#pragma unroll
            for (int fn = 0; fn < 5; ++fn)
                acc[fm][fn] = __builtin_amdgcn_mfma_f32_16x16x32_bf16(
                    af[fm], bfr[fn], acc[fm][fn], 0, 0, 0);
    }
}

__device__ __forceinline__ void barrier_fenced() {
    asm volatile("" ::: "memory");
    __builtin_amdgcn_s_barrier();
    asm volatile("" ::: "memory");
}

template<bool DIAG, bool PRE, int VM>
__device__ __forceinline__ void kstep(const u16* pA, const u16* pB, int kt,
                                      u16* bufC, u16* bufT, int w, int wr, int wc,
                                      int m16, int quad, bool dead, f32x4 acc[5][5]) {
    __builtin_amdgcn_s_waitcnt(VM);
    barrier_fenced();
    if (PRE) stage<DIAG>(pA, pB, kt + 2, bufT, w);
    if (!dead) compute<DIAG>(bufC, wr, wc, m16, quad, acc);
}

template<bool DIAG>
__device__ __forceinline__ void kloop(const u16* pA, const u16* pB, u16* ls,
                                      int w, int wr, int wc, int m16, int quad,
                                      bool dead, f32x4 acc[5][5]) {
    u16* b0 = ls;                             // 40 KB per stage buffer
    u16* b1 = ls + 20480;
    u16* b2 = ls + 40960;
    constexpr int VMF = DIAG ? 0x0F75 : 0x0F7A;   // vmcnt(5) / vmcnt(10)
    stage<DIAG>(pA, pB, 0, b0, w);
    stage<DIAG>(pA, pB, 1, b1, w);
    for (int kt = 0; kt < KIT - 3; kt += 3) {
        kstep<DIAG, true, VMF>(pA, pB, kt,     b0, b2, w, wr, wc, m16, quad, dead, acc);
        kstep<DIAG, true, VMF>(pA, pB, kt + 1, b1, b0, w, wr, wc, m16, quad, dead, acc);
        kstep<DIAG, true, VMF>(pA, pB, kt + 2, b2, b1, w, wr, wc, m16, quad, dead, acc);
    }
    kstep<DIAG, true,  VMF   >(pA, pB, KIT - 3, b0, b2, w, wr, wc, m16, quad, dead, acc);
    kstep<DIAG, false, VMF   >(pA, pB, KIT - 2, b1, b0, w, wr, wc, m16, quad, dead, acc);
    kstep<DIAG, false, 0x0F70>(pA, pB, KIT - 1, b2, b1, w, wr, wc, m16, quad, dead, acc);
}

__global__ __launch_bounds__(256) void gemm_kernel(const u16* __restrict__ nf,
                                                   int* __restrict__ meta,
                                                   float* __restrict__ P) {
    __shared__ u16 ls[61440];                 // 120 KB: 3 x (A 20KB + B 20KB)
    __shared__ int s_t;
    int A = meta[0];
    int nt = (A + TILE - 1) / TILE;
    int ntri = nt * (nt + 1) >> 1;
    if (ntri == 0) return;
    int tid = threadIdx.x, l = tid & 63, w = tid >> 6;
    int quad = l >> 4, m16 = l & 15;
    int wr = w >> 1, wc = w & 1;
    int colsw = ((l & 7) ^ (l >> 3)) << 3;    // pre-swizzled global col chunk
    int xcc;
    asm("s_getreg_b32 %0, hwreg(HW_REG_XCC_ID)" : "=s"(xcc));
    xcc &= 7;
    int* ctr = meta + 8;                      // per-kslice work-queue counters
    for (int pass = 0; pass < 8; ++pass) {
        int k = (xcc ^ pass) & 7;             // own slab first, then sweep
        for (;;) {
            if (tid == 0) s_t = atomicAdd(&ctr[k], 1);
            __syncthreads();
            int t = s_t;
            __syncthreads();                  // all read s_t before next claim
            if (t >= ntri) break;             // this queue drained
            int tt = t, bi = 0, len = nt;
            while (tt >= len) { tt -= len; --len; ++bi; }
            int bj = bi + tt;                 // bi <= bj
            int r0 = bi * TILE, c0 = bj * TILE;
            size_t kbase = (size_t)k * KSLEN + colsw;
            const u16* pA = nf + (size_t)(r0 + 40 * w + (l >> 3)) * DDIM + kbase;
            const u16* pB = nf + (size_t)(c0 + 40 * w + (l >> 3)) * DDIM + kbase;
            bool dead = (bi == bj) && (w == 2);   // diag sub-block, all gi>gj
            f32x4 acc[5][5] = {};
            if (bi == bj) kloop<true >(pA, pB, ls, w, wr, wc, m16, quad, dead, acc);
            else          kloop<false>(pA, pB, ls, w, wr, wc, m16, quad, dead, acc);
            float* dst = P + ((size_t)(t * 8 + k) * 4 + w) * 6400;
#pragma unroll
            for (int fm = 0; fm < 5; ++fm)
#pragma unroll
                for (int fn = 0; fn < 5; ++fn)
                    *(f32x4*)&dst[(fm * 5 + fn) * 256 + l * 4] = acc[fm][fn];
            __builtin_amdgcn_s_waitcnt(0x0F70);   // drain P stores: vmcnt clean
            barrier_fenced();                     // LDS reusable for next tile
        }
    }
}

// ---------------- kernel 3: reduce 8 k-partials + fused finalize ----------------
__global__ __launch_bounds__(256) void reduce_kernel(const float* __restrict__ P,
                                                     int* __restrict__ meta,
                                                     float* __restrict__ out) {
    int A = meta[0];
    int nt = (A + TILE - 1) / TILE;
    int ntri = nt * (nt + 1) >> 1;
    int tid = threadIdx.x, l = tid & 63, w = tid >> 6;
    if (ntri == 0) {                          // A==0 edge: loss = 0
        if (blockIdx.x == 0 && tid == 0) out[0] = 0.f;
        return;
    }
    int t = blockIdx.x >> 2, c = blockIdx.x & 3;
    if (t >= ntri) return;
    int tt = t, bi = 0, len = nt;             // SAME nt-triangle mapping as gemm
    while (tt >= len) { tt -= len; --len; ++bi; }
    int bj = bi + tt;
    int r0 = bi * TILE, c0 = bj * TILE;
    const float* base = P + (size_t)t * 204800 + (size_t)c * 6400;
    float local = 0.f;
#pragma unroll
    for (int mm = 0; mm < 7; ++mm) {
        int idx = mm * 256 + tid;             // f32x4 index within region [0,1600)
        if (idx < 1600) {
            const float* p0 = base + (size_t)idx * 4;
            f32x4 s = *(const f32x4*)p0;
#pragma unroll
            for (int kk = 1; kk < 8; ++kk) s += *(const f32x4*)(p0 + (size_t)kk * 25600);
            int f = idx >> 6, ln = idx & 63;
            int i = ((c >> 1) * 80) + (f / 5) * 16 + ((ln >> 4) << 2);
            int j = ((c & 1) * 80) + (f % 5) * 16 + (ln & 15);
            int gj = c0 + j;
            if (gj < A) {
#pragma unroll
                for (int r = 0; r < 4; ++r) {
                    int gi = r0 + i + r;
                    if (gi < gj) local += s[r] * s[r];
                }
            }
        }
    }
#pragma unroll
    for (int o = 32; o > 0; o >>= 1) local += __shfl_down(local, o);
    __shared__ float wred[4];
    if (l == 0) wred[w] = local;
    __syncthreads();
    if (tid == 0) {
        float bsum = wred[0] + wred[1] + wred[2] + wred[3];
        float* sqp = (float*)(meta + 1);
        float oldsq = atomicAdd(sqp, bsum);   // returning form -> tracked by vmcnt
        asm volatile("s_waitcnt vmcnt(0)" :: "v"(oldsq) : "memory");
        int oldc = atomicAdd(meta + 2, 1);    // ordered after sq at coherence pt
        if (oldc == ntri * 4 - 1) {           // last arrival: finalize loss
            float s = atomicAdd(sqp, 0.0f);   // coherent read of the full sum
            long long AA = A;
            long long na = AA * (AA - 1) / 2;
            double loss = 0.0;
            if (na > 0) loss = (double)s / ((double)DDIM * (double)DDIM) / (double)na;
            out[0] = (float)loss;
        }
    }
}

extern "C" void kernel_launch(void* const* d_in, const int* in_sizes, int n_in,
                              void* d_out, int out_size, void* d_ws, size_t ws_size,
                              hipStream_t stream) {
    (void)in_sizes; (void)n_in; (void)out_size; (void)ws_size;
    const float* wgt  = (const float*)d_in[0];
    const float* mask = (const float*)d_in[1];
    float* out = (float*)d_out;
    char*  ws  = (char*)d_ws;

    int*   meta = (int*)ws;                   // A, sq, dcnt, ctr[8] (zeroed by stats)
    u16*   nf   = (u16*)(ws + NF_OFF);
    float* P    = (float*)(ws + P_OFF);

    stats_kernel<<<NROWS, 256, 0, stream>>>(wgt, mask, nf, meta);
    gemm_kernel<<<256, 256, 0, stream>>>(nf, meta, P);
    reduce_kernel<<<NTRI160 * 4, 256, 0, stream>>>(P, meta, out);
}

// Round 12
// 142.530 us; speedup vs baseline: 1.0965x; 1.0965x over previous
//
#include <hip/hip_runtime.h>
#include <stdint.h>

#define NROWS 2048
#define DDIM  9216
#define TILE  160
#define NT160 13                      // ceil(2048/160) worst case
#define NTRI160 91                    // 13*14/2 worst-case triangle tiles
#define KS    8                       // K-slices (one per XCD)
#define KSLEN 1152                    // DDIM/KS
#define BK    64                      // K-step per stage
#define KIT   18                      // KSLEN/BK

typedef unsigned short u16;
typedef __bf16 bf16x8 __attribute__((ext_vector_type(8)));
typedef float  f32x4  __attribute__((ext_vector_type(4)));

// ws layout: meta[0..4096): [0] int A, [1] float sq, [2] int dcnt,
//            [64+k*64] ctr[k] (one 256-B line per counter, k=0..7)
//            [4096..) u16 nf[2048][9216]                    (37.75 MB)
//            [P_OFF..) float P[91][8][4][6400] partials     (74.5 MB max)
#define NF_OFF 4096ull
#define P_OFF  (NF_OFF + 2048ull * 9216ull * 2ull)
#define CTR_STRIDE 64                 // ints: 256 B between counters

__device__ __forceinline__ u16 f2bf(float f) {
    uint32_t x = __float_as_uint(f);
    x += 0x7fffu + ((x >> 16) & 1u);          // round-to-nearest-even
    return (u16)(x >> 16);
}

__device__ __forceinline__ void gload16(const u16* g, u16* l) {
    __builtin_amdgcn_global_load_lds(
        (const __attribute__((address_space(1))) uint32_t*)g,
        (__attribute__((address_space(3))) uint32_t*)l, 16, 0, 0);
}

// ---------------- kernel 1: census + per-row stats + normalize + compact --------
__global__ __launch_bounds__(256) void stats_kernel(const float* __restrict__ wgt,
                                                    const float* __restrict__ mask,
                                                    u16* __restrict__ nf,
                                                    int* __restrict__ meta) {
    int n = blockIdx.x, tid = threadIdx.x;
    int w = tid >> 6, l = tid & 63;
    int c_pre = 0, c_tot = 0;                 // census: actives before n / total
#pragma unroll
    for (int r = 0; r < 8; ++r) {
        int j = tid * 8 + r;
        int a = (mask[j] != 0.0f) ? 1 : 0;
        c_tot += a;
        if (j < n) c_pre += a;
    }
#pragma unroll
    for (int o = 32; o > 0; o >>= 1) {
        c_pre += __shfl_down(c_pre, o);
        c_tot += __shfl_down(c_tot, o);
    }
    __shared__ int sp[4], st[4];
    __shared__ float rs[4], rss[4], smean, sinv;
    if (l == 0) { sp[w] = c_pre; st[w] = c_tot; }
    __syncthreads();
    int slot = sp[0] + sp[1] + sp[2] + sp[3];
    if (n == 0 && tid == 0) {
        meta[0] = st[0] + st[1] + st[2] + st[3];  // A
        meta[1] = 0;                              // sq (float 0.0 bits)
        meta[2] = 0;                              // dcnt
#pragma unroll
        for (int q = 0; q < 8; ++q) meta[64 + q * CTR_STRIDE] = 0;  // padded ctrs
    }
    if (mask[n] == 0.0f) return;              // block-uniform: syncs below safe
    const float4* row = (const float4*)(wgt + (size_t)n * DDIM);
    float4 v[9];
    float s = 0.f, ss = 0.f;
#pragma unroll
    for (int i = 0; i < 9; ++i) {
        v[i] = row[tid + 256 * i];
        s  += v[i].x + v[i].y + v[i].z + v[i].w;
        ss += v[i].x * v[i].x + v[i].y * v[i].y + v[i].z * v[i].z + v[i].w * v[i].w;
    }
#pragma unroll
    for (int o = 32; o > 0; o >>= 1) { s += __shfl_down(s, o); ss += __shfl_down(ss, o); }
    if (l == 0) { rs[w] = s; rss[w] = ss; }
    __syncthreads();
    if (tid == 0) {
        float S  = rs[0] + rs[1] + rs[2] + rs[3];
        float SS = rss[0] + rss[1] + rss[2] + rss[3];
        float mean = S / (float)DDIM;
        float var  = SS / (float)DDIM - mean * mean;
        float sd   = sqrtf(fmaxf(var, 0.f));
        if (sd == 0.f) sd = 1.f;              // reference: std==0 -> 1
        smean = mean; sinv = 1.f / sd;
    }
    __syncthreads();
    float mean = smean, inv = sinv;
    u16* dst = nf + (size_t)slot * DDIM;
#pragma unroll
    for (int i = 0; i < 9; ++i) {
        int e = (tid + 256 * i) * 4;
        uint32_t lo = (uint32_t)f2bf((v[i].x - mean) * inv) |
                      ((uint32_t)f2bf((v[i].y - mean) * inv) << 16);
        uint32_t hi = (uint32_t)f2bf((v[i].z - mean) * inv) |
                      ((uint32_t)f2bf((v[i].w - mean) * inv) << 16);
        uint2 u; u.x = lo; u.y = hi;
        *(uint2*)(dst + e) = u;
    }
}

// ---------------- kernel 2: 160x160-tile partial GEMM, XCD-self-claimed K-split --
// R10 structure (locality PROVEN: FETCH 19.5->10.2 MB) with the claim poison
// removed: each work-queue counter now owns a private 256-B line, and none
// shares a line with meta[0]. Claims no longer serialize against each other
// or against the startup A-read. Sweep (k = xcc^pass) retained for G16-safe
// exactly-once coverage under arbitrary block placement.
template<bool DIAG>
__device__ __forceinline__ void stage(const u16* pA, const u16* pB, int kt,
                                      u16* buf, int w) {
    const u16* a = pA + kt * BK;
    u16* Ad = buf + w * 2560;                 // 40 rows x 64 u16 per wave
#pragma unroll
    for (int i = 0; i < 5; ++i)
        gload16(a + (size_t)(8 * i) * DDIM, Ad + i * 512);
    if (!DIAG) {
        const u16* b = pB + kt * BK;
        u16* Bd = buf + 10240 + w * 2560;     // B half of the stage buffer
#pragma unroll
        for (int i = 0; i < 5; ++i)
            gload16(b + (size_t)(8 * i) * DDIM, Bd + i * 512);
    }
}

template<bool DIAG>
__device__ __forceinline__ void compute(const u16* buf, int wr, int wc,
                                        int m16, int quad, f32x4 acc[5][5]) {
    const u16* Ab = buf;
    const u16* Bb = DIAG ? buf : buf + 10240;
#pragma unroll
    for (int kk = 0; kk < 2; ++kk) {
        int sw = ((((kk << 2) | quad) ^ (m16 & 7)) << 3);
        bf16x8 af[5], bfr[5];
#pragma unroll
        for (int fm = 0; fm < 5; ++fm)
            af[fm] = *(const bf16x8*)&Ab[(wr * 80 + fm * 16 + m16) * 64 + sw];
#pragma unroll
        for (int fn = 0; fn < 5; ++fn)
            bfr[fn] = *(const bf16x8*)&Bb[(wc * 80 + fn * 16 + m16) * 64 + sw];
#pragma unroll
        for (int fm = 0; fm < 5; ++fm)
#pragma unroll
            for (int fn = 0; fn < 5; ++fn)
                acc[fm][fn] = __builtin_amdgcn_mfma_f32_16x16x32_bf16(
                    af[fm], bfr[fn], acc[fm][fn], 0, 0, 0);
    }
}

__device__ __forceinline__ void barrier_fenced() {
    asm volatile("" ::: "memory");
    __builtin_amdgcn_s_barrier();
    asm volatile("" ::: "memory");
}

template<bool DIAG, bool PRE, int VM>
__device__ __forceinline__ void kstep(const u16* pA, const u16* pB, int kt,
                                      u16* bufC, u16* bufT, int w, int wr, int wc,
                                      int m16, int quad, bool dead, f32x4 acc[5][5]) {
    __builtin_amdgcn_s_waitcnt(VM);
    barrier_fenced();
    if (PRE) stage<DIAG>(pA, pB, kt + 2, bufT, w);
    if (!dead) compute<DIAG>(bufC, wr, wc, m16, quad, acc);
}

template<bool DIAG>
__device__ __forceinline__ void kloop(const u16* pA, const u16* pB, u16* ls,
                                      int w, int wr, int wc, int m16, int quad,
                                      bool dead, f32x4 acc[5][5]) {
    u16* b0 = ls;                             // 40 KB per stage buffer
    u16* b1 = ls + 20480;
    u16* b2 = ls + 40960;
    constexpr int VMF = DIAG ? 0x0F75 : 0x0F7A;   // vmcnt(5) / vmcnt(10)
    stage<DIAG>(pA, pB, 0, b0, w);
    stage<DIAG>(pA, pB, 1, b1, w);
    for (int kt = 0; kt < KIT - 3; kt += 3) {
        kstep<DIAG, true, VMF>(pA, pB, kt,     b0, b2, w, wr, wc, m16, quad, dead, acc);
        kstep<DIAG, true, VMF>(pA, pB, kt + 1, b1, b0, w, wr, wc, m16, quad, dead, acc);
        kstep<DIAG, true, VMF>(pA, pB, kt + 2, b2, b1, w, wr, wc, m16, quad, dead, acc);
    }
    kstep<DIAG, true,  VMF   >(pA, pB, KIT - 3, b0, b2, w, wr, wc, m16, quad, dead, acc);
    kstep<DIAG, false, VMF   >(pA, pB, KIT - 2, b1, b0, w, wr, wc, m16, quad, dead, acc);
    kstep<DIAG, false, 0x0F70>(pA, pB, KIT - 1, b2, b1, w, wr, wc, m16, quad, dead, acc);
}

__global__ __launch_bounds__(256) void gemm_kernel(const u16* __restrict__ nf,
                                                   int* __restrict__ meta,
                                                   float* __restrict__ P) {
    __shared__ u16 ls[61440];                 // 120 KB: 3 x (A 20KB + B 20KB)
    __shared__ int s_t;
    int A = meta[0];
    int nt = (A + TILE - 1) / TILE;
    int ntri = nt * (nt + 1) >> 1;
    if (ntri == 0) return;
    int tid = threadIdx.x, l = tid & 63, w = tid >> 6;
    int quad = l >> 4, m16 = l & 15;
    int wr = w >> 1, wc = w & 1;
    int colsw = ((l & 7) ^ (l >> 3)) << 3;    // pre-swizzled global col chunk
    int xcc;
    asm("s_getreg_b32 %0, hwreg(HW_REG_XCC_ID)" : "=s"(xcc));
    xcc &= 7;
    for (int pass = 0; pass < 8; ++pass) {
        int k = (xcc ^ pass) & 7;             // own slab first, then sweep
        int* ctrk = meta + 64 + k * CTR_STRIDE;   // private 256-B line
        for (;;) {
            if (tid == 0) s_t = atomicAdd(ctrk, 1);
            __syncthreads();
            int t = s_t;
            __syncthreads();                  // all read s_t before next claim
            if (t >= ntri) break;             // this queue drained
            int tt = t, bi = 0, len = nt;
            while (tt >= len) { tt -= len; --len; ++bi; }
            int bj = bi + tt;                 // bi <= bj
            int r0 = bi * TILE, c0 = bj * TILE;
            size_t kbase = (size_t)k * KSLEN + colsw;
            const u16* pA = nf + (size_t)(r0 + 40 * w + (l >> 3)) * DDIM + kbase;
            const u16* pB = nf + (size_t)(c0 + 40 * w + (l >> 3)) * DDIM + kbase;
            bool dead = (bi == bj) && (w == 2);   // diag sub-block, all gi>gj
            f32x4 acc[5][5] = {};
            if (bi == bj) kloop<true >(pA, pB, ls, w, wr, wc, m16, quad, dead, acc);
            else          kloop<false>(pA, pB, ls, w, wr, wc, m16, quad, dead, acc);
            float* dst = P + ((size_t)(t * 8 + k) * 4 + w) * 6400;
#pragma unroll
            for (int fm = 0; fm < 5; ++fm)
#pragma unroll
                for (int fn = 0; fn < 5; ++fn)
                    *(f32x4*)&dst[(fm * 5 + fn) * 256 + l * 4] = acc[fm][fn];
            __builtin_amdgcn_s_waitcnt(0x0F70);   // drain P stores: vmcnt clean
            barrier_fenced();                     // LDS reusable for next tile
        }
    }
}

// ---------------- kernel 3: reduce 8 k-partials + fused finalize ----------------
__global__ __launch_bounds__(256) void reduce_kernel(const float* __restrict__ P,
                                                     int* __restrict__ meta,
                                                     float* __restrict__ out) {
    int A = meta[0];
    int nt = (A + TILE - 1) / TILE;
    int ntri = nt * (nt + 1) >> 1;
    int tid = threadIdx.x, l = tid & 63, w = tid >> 6;
    if (ntri == 0) {                          // A==0 edge: loss = 0
        if (blockIdx.x == 0 && tid == 0) out[0] = 0.f;
        return;
    }
    int t = blockIdx.x >> 2, c = blockIdx.x & 3;
    if (t >= ntri) return;
    int tt = t, bi = 0, len = nt;             // SAME nt-triangle mapping as gemm
    while (tt >= len) { tt -= len; --len; ++bi; }
    int bj = bi + tt;
    int r0 = bi * TILE, c0 = bj * TILE;
    const float* base = P + (size_t)t * 204800 + (size_t)c * 6400;
    float local = 0.f;
#pragma unroll
    for (int mm = 0; mm < 7; ++mm) {
        int idx = mm * 256 + tid;             // f32x4 index within region [0,1600)
        if (idx < 1600) {
            const float* p0 = base + (size_t)idx * 4;
            f32x4 s = *(const f32x4*)p0;
#pragma unroll
            for (int kk = 1; kk < 8; ++kk) s += *(const f32x4*)(p0 + (size_t)kk * 25600);
            int f = idx >> 6, ln = idx & 63;
            int i = ((c >> 1) * 80) + (f / 5) * 16 + ((ln >> 4) << 2);
            int j = ((c & 1) * 80) + (f % 5) * 16 + (ln & 15);
            int gj = c0 + j;
            if (gj < A) {
#pragma unroll
                for (int r = 0; r < 4; ++r) {
                    int gi = r0 + i + r;
                    if (gi < gj) local += s[r] * s[r];
                }
            }
        }
    }
#pragma unroll
    for (int o = 32; o > 0; o >>= 1) local += __shfl_down(local, o);
    __shared__ float wred[4];
    if (l == 0) wred[w] = local;
    __syncthreads();
    if (tid == 0) {
        float bsum = wred[0] + wred[1] + wred[2] + wred[3];
        float* sqp = (float*)(meta + 1);
        float oldsq = atomicAdd(sqp, bsum);   // returning form -> tracked by vmcnt
        asm volatile("s_waitcnt vmcnt(0)" :: "v"(oldsq) : "memory");
        int oldc = atomicAdd(meta + 2, 1);    // ordered after sq at coherence pt
        if (oldc == ntri * 4 - 1) {           // last arrival: finalize loss
            float s = atomicAdd(sqp, 0.0f);   // coherent read of the full sum
            long long AA = A;
            long long na = AA * (AA - 1) / 2;
            double loss = 0.0;
            if (na > 0) loss = (double)s / ((double)DDIM * (double)DDIM) / (double)na;
            out[0] = (float)loss;
        }
    }
}

extern "C" void kernel_launch(void* const* d_in, const int* in_sizes, int n_in,
                              void* d_out, int out_size, void* d_ws, size_t ws_size,
                              hipStream_t stream) {
    (void)in_sizes; (void)n_in; (void)out_size; (void)ws_size;
    const float* wgt  = (const float*)d_in[0];
    const float* mask = (const float*)d_in[1];
    float* out = (float*)d_out;
    char*  ws  = (char*)d_ws;

    int*   meta = (int*)ws;                   // A, sq, dcnt, padded ctr[8]
    u16*   nf   = (u16*)(ws + NF_OFF);
    float* P    = (float*)(ws + P_OFF);

    stats_kernel<<<NROWS, 256, 0, stream>>>(wgt, mask, nf, meta);
    gemm_kernel<<<256, 256, 0, stream>>>(nf, meta, P);
    reduce_kernel<<<NTRI160 * 4, 256, 0, stream>>>(P, meta, out);
}

// Round 13
// 133.003 us; speedup vs baseline: 1.1750x; 1.0716x over previous
//
#include <hip/hip_runtime.h>
#include <stdint.h>

#define NROWS 2048
#define DDIM  9216
#define TILE  160
#define NT160 13                      // ceil(2048/160) worst case
#define NTRI160 91                    // 13*14/2 worst-case triangle tiles
#define KS    8                       // K-slices (one per XCD)
#define KSLEN 1152                    // DDIM/KS
#define BK    64                      // K-step per stage
#define KIT   18                      // KSLEN/BK

typedef unsigned short u16;
typedef __bf16 bf16x8 __attribute__((ext_vector_type(8)));
typedef float  f32x4  __attribute__((ext_vector_type(4)));

// ws layout: meta[0..4096): [0] int A, [4] float sq, [8] int dcnt
//            [4096..) u16 nf[2048][9216]                    (37.75 MB)
//            [P_OFF..) float P[91][8][4][6400] partials     (74.5 MB max)
#define NF_OFF 4096ull
#define P_OFF  (NF_OFF + 2048ull * 9216ull * 2ull)

__device__ __forceinline__ u16 f2bf(float f) {
    uint32_t x = __float_as_uint(f);
    x += 0x7fffu + ((x >> 16) & 1u);          // round-to-nearest-even
    return (u16)(x >> 16);
}

__device__ __forceinline__ void gload16(const u16* g, u16* l) {
    __builtin_amdgcn_global_load_lds(
        (const __attribute__((address_space(1))) uint32_t*)g,
        (__attribute__((address_space(3))) uint32_t*)l, 16, 0, 0);
}

// ---------------- kernel 1: census + per-row stats + normalize + compact --------
// No memset dependency: compaction slot = #active rows with index < n, computed
// by an 8 KB L2-hot census of the mask per block (replaces the cnt atomic).
// Block 0 publishes A and zeroes sq/dcnt for the reduce dispatch (race-free:
// consumers are later dispatches on the same stream).
__global__ __launch_bounds__(256) void stats_kernel(const float* __restrict__ wgt,
                                                    const float* __restrict__ mask,
                                                    u16* __restrict__ nf,
                                                    int* __restrict__ meta) {
    int n = blockIdx.x, tid = threadIdx.x;
    int w = tid >> 6, l = tid & 63;
    int c_pre = 0, c_tot = 0;                 // census: actives before n / total
#pragma unroll
    for (int r = 0; r < 8; ++r) {
        int j = tid * 8 + r;
        int a = (mask[j] != 0.0f) ? 1 : 0;
        c_tot += a;
        if (j < n) c_pre += a;
    }
#pragma unroll
    for (int o = 32; o > 0; o >>= 1) {
        c_pre += __shfl_down(c_pre, o);
        c_tot += __shfl_down(c_tot, o);
    }
    __shared__ int sp[4], st[4];
    __shared__ float rs[4], rss[4], smean, sinv;
    if (l == 0) { sp[w] = c_pre; st[w] = c_tot; }
    __syncthreads();
    int slot = sp[0] + sp[1] + sp[2] + sp[3];
    if (n == 0 && tid == 0) {
        meta[0] = st[0] + st[1] + st[2] + st[3];  // A
        meta[1] = 0;                              // sq (float 0.0 bits)
        meta[2] = 0;                              // dcnt
    }
    if (mask[n] == 0.0f) return;              // block-uniform: syncs below safe
    const float4* row = (const float4*)(wgt + (size_t)n * DDIM);
    float4 v[9];
    float s = 0.f, ss = 0.f;
#pragma unroll
    for (int i = 0; i < 9; ++i) {
        v[i] = row[tid + 256 * i];
        s  += v[i].x + v[i].y + v[i].z + v[i].w;
        ss += v[i].x * v[i].x + v[i].y * v[i].y + v[i].z * v[i].z + v[i].w * v[i].w;
    }
#pragma unroll
    for (int o = 32; o > 0; o >>= 1) { s += __shfl_down(s, o); ss += __shfl_down(ss, o); }
    if (l == 0) { rs[w] = s; rss[w] = ss; }
    __syncthreads();
    if (tid == 0) {
        float S  = rs[0] + rs[1] + rs[2] + rs[3];
        float SS = rss[0] + rss[1] + rss[2] + rss[3];
        float mean = S / (float)DDIM;
        float var  = SS / (float)DDIM - mean * mean;
        float sd   = sqrtf(fmaxf(var, 0.f));
        if (sd == 0.f) sd = 1.f;              // reference: std==0 -> 1
        smean = mean; sinv = 1.f / sd;
    }
    __syncthreads();
    float mean = smean, inv = sinv;
    u16* dst = nf + (size_t)slot * DDIM;
#pragma unroll
    for (int i = 0; i < 9; ++i) {
        int e = (tid + 256 * i) * 4;
        uint32_t lo = (uint32_t)f2bf((v[i].x - mean) * inv) |
                      ((uint32_t)f2bf((v[i].y - mean) * inv) << 16);
        uint32_t hi = (uint32_t)f2bf((v[i].z - mean) * inv) |
                      ((uint32_t)f2bf((v[i].w - mean) * inv) << 16);
        uint2 u; u.x = lo; u.y = hi;
        *(uint2*)(dst + e) = u;
    }
}

// ---------------- kernel 2: 160x160-tile partial GEMM, K-split by 8 ----------------
// R6/R9 core — best measured configuration (133.9 us total). 224 active
// blocks <= 256 CUs, static bid -> (tile, kslice) mapping, 4 waves x 80x80
// quadrant, 3-buffer 2-deep pipeline, 120 KB LDS, one barrier per K-step,
// counted vmcnt. A/B-tested against XCD-self-claimed work queues (R10/R12):
// claiming halves HBM fetch but its atomic machinery costs more than the
// locality buys (gemm is latency-bound, not HBM-bound) — static wins.
template<bool DIAG>
__device__ __forceinline__ void stage(const u16* pA, const u16* pB, int kt,
                                      u16* buf, int w) {
    const u16* a = pA + kt * BK;
    u16* Ad = buf + w * 2560;                 // 40 rows x 64 u16 per wave
#pragma unroll
    for (int i = 0; i < 5; ++i)
        gload16(a + (size_t)(8 * i) * DDIM, Ad + i * 512);
    if (!DIAG) {
        const u16* b = pB + kt * BK;
        u16* Bd = buf + 10240 + w * 2560;     // B half of the stage buffer
#pragma unroll
        for (int i = 0; i < 5; ++i)
            gload16(b + (size_t)(8 * i) * DDIM, Bd + i * 512);
    }
}

template<bool DIAG>
__device__ __forceinline__ void compute(const u16* buf, int wr, int wc,
                                        int m16, int quad, f32x4 acc[5][5]) {
    const u16* Ab = buf;
    const u16* Bb = DIAG ? buf : buf + 10240;
#pragma unroll
    for (int kk = 0; kk < 2; ++kk) {
        int sw = ((((kk << 2) | quad) ^ (m16 & 7)) << 3);
        bf16x8 af[5], bfr[5];
#pragma unroll
        for (int fm = 0; fm < 5; ++fm)
            af[fm] = *(const bf16x8*)&Ab[(wr * 80 + fm * 16 + m16) * 64 + sw];
#pragma unroll
        for (int fn = 0; fn < 5; ++fn)
            bfr[fn] = *(const bf16x8*)&Bb[(wc * 80 + fn * 16 + m16) * 64 + sw];
#pragma unroll
        for (int fm = 0; fm < 5; ++fm)
#pragma unroll
            for (int fn = 0; fn < 5; ++fn)
                acc[fm][fn] = __builtin_amdgcn_mfma_f32_16x16x32_bf16(
                    af[fm], bfr[fn], acc[fm][fn], 0, 0, 0);
    }
}

__device__ __forceinline__ void barrier_fenced() {
    asm volatile("" ::: "memory");
    __builtin_amdgcn_s_barrier();
    asm volatile("" ::: "memory");
}

template<bool DIAG, bool PRE, int VM>
__device__ __forceinline__ void kstep(const u16* pA, const u16* pB, int kt,
                                      u16* bufC, u16* bufT, int w, int wr, int wc,
                                      int m16, int quad, bool dead, f32x4 acc[5][5]) {
    __builtin_amdgcn_s_waitcnt(VM);
    barrier_fenced();
    if (PRE) stage<DIAG>(pA, pB, kt + 2, bufT, w);
    if (!dead) compute<DIAG>(bufC, wr, wc, m16, quad, acc);
}

template<bool DIAG>
__device__ __forceinline__ void kloop(const u16* pA, const u16* pB, u16* ls,
                                      int w, int wr, int wc, int m16, int quad,
                                      bool dead, f32x4 acc[5][5]) {
    u16* b0 = ls;                             // 40 KB per stage buffer
    u16* b1 = ls + 20480;
    u16* b2 = ls + 40960;
    constexpr int VMF = DIAG ? 0x0F75 : 0x0F7A;   // vmcnt(5) / vmcnt(10)
    stage<DIAG>(pA, pB, 0, b0, w);
    stage<DIAG>(pA, pB, 1, b1, w);
    for (int kt = 0; kt < KIT - 3; kt += 3) {
        kstep<DIAG, true, VMF>(pA, pB, kt,     b0, b2, w, wr, wc, m16, quad, dead, acc);
        kstep<DIAG, true, VMF>(pA, pB, kt + 1, b1, b0, w, wr, wc, m16, quad, dead, acc);
        kstep<DIAG, true, VMF>(pA, pB, kt + 2, b2, b1, w, wr, wc, m16, quad, dead, acc);
    }
    kstep<DIAG, true,  VMF   >(pA, pB, KIT - 3, b0, b2, w, wr, wc, m16, quad, dead, acc);
    kstep<DIAG, false, VMF   >(pA, pB, KIT - 2, b1, b0, w, wr, wc, m16, quad, dead, acc);
    kstep<DIAG, false, 0x0F70>(pA, pB, KIT - 1, b2, b1, w, wr, wc, m16, quad, dead, acc);
}

__global__ __launch_bounds__(256) void gemm_kernel(const u16* __restrict__ nf,
                                                   const int* __restrict__ meta,
                                                   float* __restrict__ P) {
    __shared__ u16 ls[61440];                 // 120 KB: 3 x (A 20KB + B 20KB)
    int A = meta[0];
    int nt = (A + TILE - 1) / TILE;
    int ntri = nt * (nt + 1) >> 1;
    int bid = blockIdx.x;
    int t = bid >> 3, k = bid & 7;            // k = bid%8 -> XCD k (round-robin)
    if (t >= ntri) return;                    // contiguous active prefix
    int tt = t, bi = 0, len = nt;
    while (tt >= len) { tt -= len; --len; ++bi; }
    int bj = bi + tt;                         // bi <= bj
    int r0 = bi * TILE, c0 = bj * TILE;
    int tid = threadIdx.x, l = tid & 63, w = tid >> 6;
    int quad = l >> 4, m16 = l & 15;
    int wr = w >> 1, wc = w & 1;
    int colsw = ((l & 7) ^ (l >> 3)) << 3;    // pre-swizzled global col chunk
    size_t kbase = (size_t)k * KSLEN + colsw;
    const u16* pA = nf + (size_t)(r0 + 40 * w + (l >> 3)) * DDIM + kbase;
    const u16* pB = nf + (size_t)(c0 + 40 * w + (l >> 3)) * DDIM + kbase;
    bool dead = (bi == bj) && (w == 2);       // diag sub-block, all gi>gj
    f32x4 acc[5][5] = {};
    if (bi == bj) kloop<true >(pA, pB, ls, w, wr, wc, m16, quad, dead, acc);
    else          kloop<false>(pA, pB, ls, w, wr, wc, m16, quad, dead, acc);
    // frag-major coalesced partial store: P[(t*8+k)*4 + w][frag][lane][reg]
    float* dst = P + ((size_t)(t * 8 + k) * 4 + w) * 6400;
#pragma unroll
    for (int fm = 0; fm < 5; ++fm)
#pragma unroll
        for (int fn = 0; fn < 5; ++fn)
            *(f32x4*)&dst[(fm * 5 + fn) * 256 + l * 4] = acc[fm][fn];
}

// ---------------- kernel 3: reduce 8 k-partials + fused finalize ----------------
// R6 reduce + last-arrival finalize using ATOMICS ONLY (no threadfence / L2
// flush): atomicAdd(sq) in returning form + explicit vmcnt(0) guarantees the
// sq update reached the coherence point before the dcnt bump; the last block
// re-reads sq via atomicAdd(sq, 0) and writes the loss. Removes final_kernel.
__global__ __launch_bounds__(256) void reduce_kernel(const float* __restrict__ P,
                                                     int* __restrict__ meta,
                                                     float* __restrict__ out) {
    int A = meta[0];
    int nt = (A + TILE - 1) / TILE;
    int ntri = nt * (nt + 1) >> 1;
    int tid = threadIdx.x, l = tid & 63, w = tid >> 6;
    if (ntri == 0) {                          // A==0 edge: loss = 0
        if (blockIdx.x == 0 && tid == 0) out[0] = 0.f;
        return;
    }
    int t = blockIdx.x >> 2, c = blockIdx.x & 3;
    if (t >= ntri) return;
    int tt = t, bi = 0, len = nt;             // SAME nt-triangle mapping as gemm
    while (tt >= len) { tt -= len; --len; ++bi; }
    int bj = bi + tt;
    int r0 = bi * TILE, c0 = bj * TILE;
    const float* base = P + (size_t)t * 204800 + (size_t)c * 6400;
    float local = 0.f;
#pragma unroll
    for (int mm = 0; mm < 7; ++mm) {
        int idx = mm * 256 + tid;             // f32x4 index within region [0,1600)
        if (idx < 1600) {
            const float* p0 = base + (size_t)idx * 4;
            f32x4 s = *(const f32x4*)p0;
#pragma unroll
            for (int kk = 1; kk < 8; ++kk) s += *(const f32x4*)(p0 + (size_t)kk * 25600);
            int f = idx >> 6, ln = idx & 63;
            int i = ((c >> 1) * 80) + (f / 5) * 16 + ((ln >> 4) << 2);
            int j = ((c & 1) * 80) + (f % 5) * 16 + (ln & 15);
            int gj = c0 + j;
            if (gj < A) {
#pragma unroll
                for (int r = 0; r < 4; ++r) {
                    int gi = r0 + i + r;
                    if (gi < gj) local += s[r] * s[r];
                }
            }
        }
    }
#pragma unroll
    for (int o = 32; o > 0; o >>= 1) local += __shfl_down(local, o);
    __shared__ float wred[4];
    if (l == 0) wred[w] = local;
    __syncthreads();
    if (tid == 0) {
        float bsum = wred[0] + wred[1] + wred[2] + wred[3];
        float* sqp = (float*)(meta + 1);
        float oldsq = atomicAdd(sqp, bsum);   // returning form -> tracked by vmcnt
        asm volatile("s_waitcnt vmcnt(0)" :: "v"(oldsq) : "memory");
        int oldc = atomicAdd(meta + 2, 1);    // ordered after sq at coherence pt
        if (oldc == ntri * 4 - 1) {           // last arrival: finalize loss
            float s = atomicAdd(sqp, 0.0f);   // coherent read of the full sum
            long long AA = A;
            long long na = AA * (AA - 1) / 2;
            double loss = 0.0;
            if (na > 0) loss = (double)s / ((double)DDIM * (double)DDIM) / (double)na;
            out[0] = (float)loss;
        }
    }
}

extern "C" void kernel_launch(void* const* d_in, const int* in_sizes, int n_in,
                              void* d_out, int out_size, void* d_ws, size_t ws_size,
                              hipStream_t stream) {
    (void)in_sizes; (void)n_in; (void)out_size; (void)ws_size;
    const float* wgt  = (const float*)d_in[0];
    const float* mask = (const float*)d_in[1];
    float* out = (float*)d_out;
    char*  ws  = (char*)d_ws;

    int*   meta = (int*)ws;                   // A, sq, dcnt (zeroed by stats blk 0)
    u16*   nf   = (u16*)(ws + NF_OFF);
    float* P    = (float*)(ws + P_OFF);

    stats_kernel<<<NROWS, 256, 0, stream>>>(wgt, mask, nf, meta);
    gemm_kernel<<<NTRI160 * KS, 256, 0, stream>>>(nf, meta, P);
    reduce_kernel<<<NTRI160 * 4, 256, 0, stream>>>(P, meta, out);
}